// Round 3
// baseline (752.456 us; speedup 1.0000x reference)
//
#include <hip/hip_runtime.h>

// GKAT layer, restructured:
//   ret = elu( (S @ (C @ V_ext)) / (S @ rowsum(C) + eps) )
// where S = exp(scale*Q@K^T - M_i), M_i = ||Q_i|| * max_j ||K_j|| * scale
// (Cauchy-Schwarz upper bound on rowmax; exact rowmax cancels in the ratio).
// V_ext = [V | ones | pad] so rowsum(C) rides as column 128 of C@V_ext.
//
// R3: every GEMM gets >=2 co-resident blocks/CU (m114 wave overlap):
//   qkv  : 1 block = 64 rows x 1 W matrix, single barrier, grid 384
//   cv   : M=128, k-split 8 -> grid 512 (2/CU), fp32 atomic partials
//   flash: key-split 8 -> grid 512 (2/CU)

#define SCALE 0.088388347648318447f   // 1/sqrt(128)

typedef __attribute__((ext_vector_type(8))) short bf16x8;   // 8 bf16 (4 VGPRs)
typedef __attribute__((ext_vector_type(4))) short bf16x4;   // 8-byte LDS loads
typedef __attribute__((ext_vector_type(4))) float f32x4;

static __device__ __forceinline__ unsigned short f2bf(float f) {
    unsigned u = __float_as_uint(f);
    u = (u + 0x7fffu + ((u >> 16) & 1u)) >> 16;   // RNE
    return (unsigned short)u;
}
static __device__ __forceinline__ float bf2f(unsigned short b) {
    return __uint_as_float(((unsigned)b) << 16);
}
static __device__ __forceinline__ bf16x8 pack8(const float4& a, const float4& b) {
    bf16x8 v;
    v[0] = (short)f2bf(a.x); v[1] = (short)f2bf(a.y);
    v[2] = (short)f2bf(a.z); v[3] = (short)f2bf(a.w);
    v[4] = (short)f2bf(b.x); v[5] = (short)f2bf(b.y);
    v[6] = (short)f2bf(b.z); v[7] = (short)f2bf(b.w);
    return v;
}

// ---------------------------------------------------------------------------
// Kernel 1 v3: one block = 64 feat rows x one full W matrix (128 cols, K=256).
// Stage A(64x256) + B(128x256, transposed) once -> ONE barrier -> 8 k-iters
// of pure MFMA. grid (128, 3): blockIdx.y selects Wq/Wk/Wv.
// ---------------------------------------------------------------------------
__global__ __launch_bounds__(512) void qkv_mfma(
    const float* __restrict__ feat, const float* __restrict__ Wq,
    const float* __restrict__ Wk, const float* __restrict__ Wv,
    unsigned short* __restrict__ Qb, unsigned short* __restrict__ Kb,
    unsigned short* __restrict__ VbT) {
    __shared__ unsigned short As[64][264];   // stride 264 shorts: 16B-aligned, 2-way banks (free)
    __shared__ unsigned short Bs[128][264];
    const int tid = threadIdx.x;
    const int m0 = blockIdx.x * 64;
    const int mat = blockIdx.y;
    const float* W = (mat == 0) ? Wq : (mat == 1) ? Wk : Wv;
    const int lane = tid & 63, wv = tid >> 6;
    const int wm = wv & 3, wn = wv >> 2;     // wave: 16 rows x 64 cols
    const int ln15 = lane & 15, quad = lane >> 4;

    // stage A: 64 rows x 256 cols fp32 -> bf16 (4 slots of 8 floats / thread)
    #pragma unroll
    for (int i = 0; i < 4; i++) {
        int s = tid + i * 512;
        int r = s >> 5, c8 = s & 31;
        const float* p = feat + (size_t)(m0 + r) * 256 + c8 * 8;
        const float4 f0 = *(const float4*)p;
        const float4 f1 = *(const float4*)(p + 4);
        *(bf16x8*)&As[r][c8 * 8] = pack8(f0, f1);
    }
    // stage B: W[k][n] fp32 -> Bs[n][k] bf16 (transpose; 16 float4 / thread)
    #pragma unroll
    for (int i = 0; i < 16; i++) {
        int s = tid + i * 512;               // 8192 float4 slots
        int k = s >> 5, n4 = (s & 31) * 4;
        const float4 f = *(const float4*)(W + (size_t)k * 128 + n4);
        Bs[n4 + 0][k] = f2bf(f.x); Bs[n4 + 1][k] = f2bf(f.y);
        Bs[n4 + 2][k] = f2bf(f.z); Bs[n4 + 3][k] = f2bf(f.w);
    }
    __syncthreads();   // the only barrier

    f32x4 acc[4];
    #pragma unroll
    for (int t = 0; t < 4; t++) acc[t] = f32x4{0.f, 0.f, 0.f, 0.f};
    #pragma unroll
    for (int ks = 0; ks < 8; ks++) {
        bf16x8 af = *(const bf16x8*)&As[wm * 16 + ln15][ks * 32 + quad * 8];
        #pragma unroll
        for (int t = 0; t < 4; t++) {
            bf16x8 bf = *(const bf16x8*)&Bs[wn * 64 + t * 16 + ln15][ks * 32 + quad * 8];
            acc[t] = __builtin_amdgcn_mfma_f32_16x16x32_bf16(af, bf, acc[t], 0, 0, 0);
        }
    }
    // epilogue: C/D layout col=lane&15, row=quad*4+reg
    #pragma unroll
    for (int t = 0; t < 4; t++) {
        int n = wn * 64 + t * 16 + ln15;
        int mb = m0 + wm * 16 + quad * 4;
        if (mat == 2) {   // V: transposed store, 4 consecutive m -> 8B store
            ushort4 w;
            w.x = f2bf(acc[t][0]); w.y = f2bf(acc[t][1]);
            w.z = f2bf(acc[t][2]); w.w = f2bf(acc[t][3]);
            *(ushort4*)(VbT + (size_t)n * 8192 + mb) = w;
        } else {
            unsigned short* dst = (mat == 0) ? Qb : Kb;
            #pragma unroll
            for (int reg = 0; reg < 4; reg++)
                dst[(size_t)(mb + reg) * 128 + n] = f2bf(acc[t][reg]);
        }
    }
    if (mat == 2) {   // V_ext rows 128..191 for this m-range: ones row + zeros
        #pragma unroll
        for (int i = 0; i < 8; i++) {
            int idx = tid + i * 512;          // 64 rows x 64 cols
            int rr = idx >> 6, c = idx & 63;
            VbT[(size_t)(128 + rr) * 8192 + m0 + c] =
                (rr == 0) ? (unsigned short)0x3F80 : (unsigned short)0;
        }
    }
}

// ---------------------------------------------------------------------------
// Kernel 2: row norms of Q, global max row-norm^2 of K (unchanged).
// ---------------------------------------------------------------------------
__global__ __launch_bounds__(128) void norms_kernel(
    const unsigned short* __restrict__ Qb, const unsigned short* __restrict__ Kb,
    float* __restrict__ qn2, unsigned* __restrict__ knmax) {
    const int r = blockIdx.x, j = threadIdx.x;
    float q = bf2f(Qb[(size_t)r * 128 + j]);
    float k = bf2f(Kb[(size_t)r * 128 + j]);
    float sq = q * q, sk = k * k;
    for (int m = 1; m < 64; m <<= 1) {
        sq += __shfl_xor(sq, m, 64);
        sk += __shfl_xor(sk, m, 64);
    }
    __shared__ float s0[2], s1[2];
    if ((j & 63) == 0) { s0[j >> 6] = sq; s1[j >> 6] = sk; }
    __syncthreads();
    if (j == 0)  qn2[r] = s0[0] + s0[1];
    if (j == 64) atomicMax(knmax, __float_as_uint(s1[0] + s1[1]));
}

// ---------------------------------------------------------------------------
// Kernel 3 v3: CVf32 += (C @ V_ext)^T partials.  M=128/block, 512 thr,
// k-split 8 -> grid 512 (2 blocks/CU).  Dist-2 reg prefetch on A and B.
// Output fp32 [160][8192] via atomicAdd (zeroed at launch).
// ---------------------------------------------------------------------------
__global__ __launch_bounds__(512, 4) void cv_kernel(
    const float* __restrict__ C, const unsigned short* __restrict__ VbT,
    float* __restrict__ CVf32) {
    __shared__ unsigned short As[128][72];   // 18 KB
    __shared__ unsigned short Bs[192][72];   // 27 KB   (45 KB total -> 2 blocks/CU)
    const int tid = threadIdx.x;
    const int rg = blockIdx.x >> 3, sp = blockIdx.x & 7;
    const int m0 = rg * 128;
    const int k0 = sp * 1024;                // 16 chunks of 64
    const int lane = tid & 63, wv = tid >> 6;
    const int p4 = wv & 3, h2 = wv >> 2;     // rows 32*p4..+32, n-half 80*h2
    const int ln15 = lane & 15, quad = lane >> 4;

    const int ar = tid >> 3, ac8 = tid & 7;  // A: 2 slots/thread (rows ar, ar+64)
    const float* Ab0 = C + (size_t)(m0 + ar) * 8192 + k0 + ac8 * 8;
    const float* Ab1 = Ab0 + (size_t)64 * 8192;

    float4 pa[2][4];   // [set][slot0 lo/hi, slot1 lo/hi]
    bf16x8 pb[2][3];
    #pragma unroll
    for (int d = 0; d < 2; d++) {
        const int kb = d * 64;
        pa[d][0] = *(const float4*)(Ab0 + kb); pa[d][1] = *(const float4*)(Ab0 + kb + 4);
        pa[d][2] = *(const float4*)(Ab1 + kb); pa[d][3] = *(const float4*)(Ab1 + kb + 4);
        #pragma unroll
        for (int i = 0; i < 3; i++) {
            int s = tid + i * 512;           // 192 x 8 slots
            pb[d][i] = *(const bf16x8*)(VbT + (size_t)(s >> 3) * 8192 + k0 + kb + (s & 7) * 8);
        }
    }

    f32x4 acc[2][5];
    #pragma unroll
    for (int mt = 0; mt < 2; mt++)
        #pragma unroll
        for (int t = 0; t < 5; t++) acc[mt][t] = f32x4{0.f, 0.f, 0.f, 0.f};

    for (int c = 0; c < 16; c += 2) {
        #pragma unroll
        for (int d = 0; d < 2; d++) {
            __syncthreads();   // prev chunk's LDS reads done
            *(bf16x8*)&As[ar][ac8 * 8]      = pack8(pa[d][0], pa[d][1]);
            *(bf16x8*)&As[ar + 64][ac8 * 8] = pack8(pa[d][2], pa[d][3]);
            #pragma unroll
            for (int i = 0; i < 3; i++) {
                int s = tid + i * 512;
                *(bf16x8*)&Bs[s >> 3][(s & 7) * 8] = pb[d][i];
            }
            if (c + d + 2 < 16) {            // prefetch chunk c+d+2 into set d
                const int kb = (c + d + 2) * 64;
                pa[d][0] = *(const float4*)(Ab0 + kb); pa[d][1] = *(const float4*)(Ab0 + kb + 4);
                pa[d][2] = *(const float4*)(Ab1 + kb); pa[d][3] = *(const float4*)(Ab1 + kb + 4);
                #pragma unroll
                for (int i = 0; i < 3; i++) {
                    int s = tid + i * 512;
                    pb[d][i] = *(const bf16x8*)(VbT + (size_t)(s >> 3) * 8192 + k0 + kb + (s & 7) * 8);
                }
            }
            __syncthreads();   // staging visible
            #pragma unroll
            for (int k2 = 0; k2 < 2; k2++) {
                bf16x8 a0 = *(const bf16x8*)&As[p4 * 32 + ln15][k2 * 32 + quad * 8];
                bf16x8 a1 = *(const bf16x8*)&As[p4 * 32 + 16 + ln15][k2 * 32 + quad * 8];
                #pragma unroll
                for (int t = 0; t < 5; t++) {
                    bf16x8 bf = *(const bf16x8*)&Bs[h2 * 80 + t * 16 + ln15][k2 * 32 + quad * 8];
                    acc[0][t] = __builtin_amdgcn_mfma_f32_16x16x32_bf16(a0, bf, acc[0][t], 0, 0, 0);
                    acc[1][t] = __builtin_amdgcn_mfma_f32_16x16x32_bf16(a1, bf, acc[1][t], 0, 0, 0);
                }
            }
        }
    }
    #pragma unroll
    for (int mt = 0; mt < 2; mt++)
        #pragma unroll
        for (int t = 0; t < 5; t++) {
            int n = h2 * 80 + t * 16 + ln15;
            int mb = m0 + p4 * 32 + mt * 16 + quad * 4;
            #pragma unroll
            for (int reg = 0; reg < 4; reg++)
                atomicAdd(&CVf32[(size_t)n * 8192 + mb + reg], acc[mt][t][reg]);
        }
}

// ---------------------------------------------------------------------------
// Kernel 3b: CVbT bf16 = CVf32 (rows 0..159).
// ---------------------------------------------------------------------------
__global__ __launch_bounds__(256) void cvt_kernel(
    const float* __restrict__ CVf32, unsigned short* __restrict__ CVbT) {
    int idx = blockIdx.x * 256 + threadIdx.x;    // 163840 slots of 8
    const float* p = CVf32 + (size_t)idx * 8;
    const float4 f0 = *(const float4*)p;
    const float4 f1 = *(const float4*)(p + 4);
    *(bf16x8*)(CVbT + (size_t)idx * 8) = pack8(f0, f1);
}

// ---------------------------------------------------------------------------
// Kernel 4 v3: 512 thr, M=128 q-rows, key-split 8 -> grid 512 (2 blocks/CU).
// Per 64-key chunk: QK -> exp -> Ps -> PV.  Partials atomicAdd into Of32.
// ---------------------------------------------------------------------------
__global__ __launch_bounds__(512, 4) void flash_kernel(
    const unsigned short* __restrict__ Qb, const unsigned short* __restrict__ Kb,
    const unsigned short* __restrict__ CVbT, const float* __restrict__ qn2,
    const unsigned* __restrict__ knmax, float* __restrict__ Of32) {
    __shared__ unsigned short Qs[128][136];  // 34 KB
    __shared__ unsigned short Ks[64][136];   // 17 KB
    __shared__ unsigned short Cs[192][72];   // 27 KB
    __shared__ unsigned short Ps[128][68];   // 17 KB  (stride 68: conflict-free b16 writes)
    const int tid = threadIdx.x;
    const int rg = blockIdx.x >> 3, sp = blockIdx.x & 7;
    const int i0 = rg * 128;
    const int k0 = sp * 1024;                // 16 chunks of 64 keys
    const int lane = tid & 63, wv = tid >> 6;
    const int ln15 = lane & 15, quad = lane >> 4;
    const int p4 = wv & 3;    // m-pair: rows 32*p4..+32
    const int h2 = wv >> 2;   // QK: key-half; PV: n-half

    #pragma unroll
    for (int i = 0; i < 4; i++) {            // stage Q once (128x128)
        int s = tid + i * 512;
        int r = s >> 4, cq = s & 15;
        *(bf16x8*)&Qs[r][cq * 8] = *(const bf16x8*)(Qb + (size_t)(i0 + r) * 128 + cq * 8);
    }
    const float kn2 = __uint_as_float(*knmax);
    float Msr[2][4];
    #pragma unroll
    for (int mt = 0; mt < 2; mt++)
        #pragma unroll
        for (int reg = 0; reg < 4; reg++) {
            int row = p4 * 32 + mt * 16 + quad * 4 + reg;
            Msr[mt][reg] = sqrtf(qn2[i0 + row] * kn2) * SCALE;
        }

    bf16x8 pkK[2], pkC[3];
    {
        const int kb = k0;
        #pragma unroll
        for (int i = 0; i < 2; i++) {
            int s = tid + i * 512;
            pkK[i] = *(const bf16x8*)(Kb + (size_t)(kb + (s >> 4)) * 128 + (s & 15) * 8);
        }
        #pragma unroll
        for (int i = 0; i < 3; i++) {
            int s = tid + i * 512;
            pkC[i] = *(const bf16x8*)(CVbT + (size_t)(s >> 3) * 8192 + kb + (s & 7) * 8);
        }
    }

    f32x4 acc[2][5];
    #pragma unroll
    for (int mt = 0; mt < 2; mt++)
        #pragma unroll
        for (int t = 0; t < 5; t++) acc[mt][t] = f32x4{0.f, 0.f, 0.f, 0.f};

    for (int c = 0; c < 16; c++) {
        __syncthreads();
        #pragma unroll
        for (int i = 0; i < 2; i++) {
            int s = tid + i * 512;
            *(bf16x8*)&Ks[s >> 4][(s & 15) * 8] = pkK[i];
        }
        #pragma unroll
        for (int i = 0; i < 3; i++) {
            int s = tid + i * 512;
            *(bf16x8*)&Cs[s >> 3][(s & 7) * 8] = pkC[i];
        }
        if (c + 1 < 16) {
            const int kb = k0 + (c + 1) * 64;
            #pragma unroll
            for (int i = 0; i < 2; i++) {
                int s = tid + i * 512;
                pkK[i] = *(const bf16x8*)(Kb + (size_t)(kb + (s >> 4)) * 128 + (s & 15) * 8);
            }
            #pragma unroll
            for (int i = 0; i < 3; i++) {
                int s = tid + i * 512;
                pkC[i] = *(const bf16x8*)(CVbT + (size_t)(s >> 3) * 8192 + kb + (s & 7) * 8);
            }
        }
        __syncthreads();

        // QK: rows 32*p4..+32 x keys 32*h2..+32
        f32x4 pacc[2][2];
        #pragma unroll
        for (int mt = 0; mt < 2; mt++)
            #pragma unroll
            for (int kt = 0; kt < 2; kt++) pacc[mt][kt] = f32x4{0.f, 0.f, 0.f, 0.f};
        #pragma unroll
        for (int kk = 0; kk < 4; kk++) {
            bf16x8 aq0 = *(const bf16x8*)&Qs[p4 * 32 + ln15][kk * 32 + quad * 8];
            bf16x8 aq1 = *(const bf16x8*)&Qs[p4 * 32 + 16 + ln15][kk * 32 + quad * 8];
            #pragma unroll
            for (int kt = 0; kt < 2; kt++) {
                bf16x8 bk = *(const bf16x8*)&Ks[h2 * 32 + kt * 16 + ln15][kk * 32 + quad * 8];
                pacc[0][kt] = __builtin_amdgcn_mfma_f32_16x16x32_bf16(aq0, bk, pacc[0][kt], 0, 0, 0);
                pacc[1][kt] = __builtin_amdgcn_mfma_f32_16x16x32_bf16(aq1, bk, pacc[1][kt], 0, 0, 0);
            }
        }
        #pragma unroll
        for (int mt = 0; mt < 2; mt++)
            #pragma unroll
            for (int kt = 0; kt < 2; kt++)
                #pragma unroll
                for (int reg = 0; reg < 4; reg++) {
                    int row = p4 * 32 + mt * 16 + quad * 4 + reg;
                    int key = h2 * 32 + kt * 16 + ln15;
                    float p = __expf(pacc[mt][kt][reg] * SCALE - Msr[mt][reg]);
                    Ps[row][key] = f2bf(p);
                }
        __syncthreads();

        // PV: rows 32*p4..+32 x n = 80*h2..+80  (Ps reads as 8B-aligned b64 pairs)
        #pragma unroll
        for (int ks = 0; ks < 2; ks++) {
            bf16x4 lo0 = *(const bf16x4*)&Ps[p4 * 32 + ln15][ks * 32 + quad * 8];
            bf16x4 hi0 = *(const bf16x4*)&Ps[p4 * 32 + ln15][ks * 32 + quad * 8 + 4];
            bf16x4 lo1 = *(const bf16x4*)&Ps[p4 * 32 + 16 + ln15][ks * 32 + quad * 8];
            bf16x4 hi1 = *(const bf16x4*)&Ps[p4 * 32 + 16 + ln15][ks * 32 + quad * 8 + 4];
            bf16x8 ap0, ap1;
            #pragma unroll
            for (int j = 0; j < 4; j++) {
                ap0[j] = lo0[j]; ap0[j + 4] = hi0[j];
                ap1[j] = lo1[j]; ap1[j + 4] = hi1[j];
            }
            #pragma unroll
            for (int t = 0; t < 5; t++) {
                bf16x8 bc = *(const bf16x8*)&Cs[h2 * 80 + t * 16 + ln15][ks * 32 + quad * 8];
                acc[0][t] = __builtin_amdgcn_mfma_f32_16x16x32_bf16(ap0, bc, acc[0][t], 0, 0, 0);
                acc[1][t] = __builtin_amdgcn_mfma_f32_16x16x32_bf16(ap1, bc, acc[1][t], 0, 0, 0);
            }
        }
    }
    #pragma unroll
    for (int mt = 0; mt < 2; mt++)
        #pragma unroll
        for (int t = 0; t < 5; t++)
            #pragma unroll
            for (int reg = 0; reg < 4; reg++) {
                int row = i0 + p4 * 32 + mt * 16 + quad * 4 + reg;
                int n = h2 * 80 + t * 16 + ln15;
                atomicAdd(&Of32[(size_t)row * 160 + n], acc[mt][t][reg]);
            }
}

// ---------------------------------------------------------------------------
// Kernel 5: out = elu(O / (deno + 1e-9)), deno = column 128 of Of32.
// ---------------------------------------------------------------------------
__global__ __launch_bounds__(256) void finalize_kernel(
    const float* __restrict__ Of32, float* __restrict__ out) {
    int idx = blockIdx.x * 256 + threadIdx.x;
    int i = idx >> 7, n = idx & 127;
    float deno = Of32[(size_t)i * 160 + 128] + 1e-9f;
    float v = Of32[(size_t)i * 160 + n] / deno;
    out[idx] = (v > 0.f) ? v : expm1f(v);
}

// ---------------------------------------------------------------------------
extern "C" void kernel_launch(void* const* d_in, const int* in_sizes, int n_in,
                              void* d_out, int out_size, void* d_ws, size_t ws_size,
                              hipStream_t stream) {
    const float* feat = (const float*)d_in[0];
    // d_in[1] = bg (unused scalar)
    const float* C    = (const float*)d_in[2];
    const float* Wq   = (const float*)d_in[3];
    const float* Wk   = (const float*)d_in[4];
    const float* Wv   = (const float*)d_in[5];
    float* out = (float*)d_out;

    char* ws = (char*)d_ws;
    unsigned short* Qb   = (unsigned short*)(ws + 0);          // 2 MB
    unsigned short* Kb   = (unsigned short*)(ws + 2097152);    // 2 MB
    unsigned short* VbT  = (unsigned short*)(ws + 4194304);    // 192x8192x2 = 3 MB
    float*          CVf32= (float*)(ws + 7340032);             // 160x8192x4 = 5.25 MB
    unsigned short* CVbT = (unsigned short*)(ws + 12845056);   // 192x8192x2 = 3 MB
    float*          Of32 = (float*)(ws + 15990784);            // 8192x160x4 = 5.25 MB
    float*          qn2  = (float*)(ws + 21495808);            // 32 KB
    unsigned*       knmax= (unsigned*)(ws + 21528576);         // 4 B  (~20.5 MB total)

    hipMemsetAsync(knmax, 0, 4, stream);
    hipMemsetAsync(CVf32, 0, 160 * 8192 * sizeof(float), stream);
    hipMemsetAsync(Of32, 0, 8192 * 160 * sizeof(float), stream);
    qkv_mfma<<<dim3(128, 3), 512, 0, stream>>>(feat, Wq, Wk, Wv, Qb, Kb, VbT);
    norms_kernel<<<8192, 128, 0, stream>>>(Qb, Kb, qn2, knmax);
    cv_kernel<<<512, 512, 0, stream>>>(C, VbT, CVf32);
    cvt_kernel<<<640, 256, 0, stream>>>(CVf32, CVbT);
    flash_kernel<<<512, 512, 0, stream>>>(Qb, Kb, CVbT, qn2, knmax, Of32);
    finalize_kernel<<<4096, 256, 0, stream>>>(Of32, out);
}

// Round 4
// 708.591 us; speedup vs baseline: 1.0619x; 1.0619x over previous
//
#include <hip/hip_runtime.h>

// GKAT layer, restructured:
//   ret = elu( (S @ (C @ V_ext)) / (S @ rowsum(C) + eps) )
// where S = exp(scale*Q@K^T - M_i), M_i = ||Q_i|| * max_j ||K_j|| * scale
// (Cauchy-Schwarz upper bound on rowmax; exact rowmax cancels in the ratio).
// V_ext = [V | ones | pad] so rowsum(C) rides as column 128 of C@V_ext.
//
// R4: launch_bounds 2nd arg is MIN-BLOCKS-PER-CU on hipcc (measured R3:
// (512,4) -> 64 VGPR -> spill disaster). Use (512,2) -> cap 128 VGPR.
// flash: Q lives in registers (wave only needs its own 32 rows) -> LDS
// 97->56.5 KB -> 2 blocks/CU.

#define SCALE 0.088388347648318447f   // 1/sqrt(128)

typedef __attribute__((ext_vector_type(8))) short bf16x8;   // 8 bf16 (4 VGPRs)
typedef __attribute__((ext_vector_type(4))) short bf16x4;   // 8-byte LDS loads
typedef __attribute__((ext_vector_type(4))) float f32x4;

static __device__ __forceinline__ unsigned short f2bf(float f) {
    unsigned u = __float_as_uint(f);
    u = (u + 0x7fffu + ((u >> 16) & 1u)) >> 16;   // RNE
    return (unsigned short)u;
}
static __device__ __forceinline__ float bf2f(unsigned short b) {
    return __uint_as_float(((unsigned)b) << 16);
}
static __device__ __forceinline__ bf16x8 pack8(const float4& a, const float4& b) {
    bf16x8 v;
    v[0] = (short)f2bf(a.x); v[1] = (short)f2bf(a.y);
    v[2] = (short)f2bf(a.z); v[3] = (short)f2bf(a.w);
    v[4] = (short)f2bf(b.x); v[5] = (short)f2bf(b.y);
    v[6] = (short)f2bf(b.z); v[7] = (short)f2bf(b.w);
    return v;
}

// ---------------------------------------------------------------------------
// Kernel 1: one block = 64 feat rows x one full W matrix. Single barrier.
// ---------------------------------------------------------------------------
__global__ __launch_bounds__(512) void qkv_mfma(
    const float* __restrict__ feat, const float* __restrict__ Wq,
    const float* __restrict__ Wk, const float* __restrict__ Wv,
    unsigned short* __restrict__ Qb, unsigned short* __restrict__ Kb,
    unsigned short* __restrict__ VbT) {
    __shared__ unsigned short As[64][264];
    __shared__ unsigned short Bs[128][264];
    const int tid = threadIdx.x;
    const int m0 = blockIdx.x * 64;
    const int mat = blockIdx.y;
    const float* W = (mat == 0) ? Wq : (mat == 1) ? Wk : Wv;
    const int lane = tid & 63, wv = tid >> 6;
    const int wm = wv & 3, wn = wv >> 2;
    const int ln15 = lane & 15, quad = lane >> 4;

    #pragma unroll
    for (int i = 0; i < 4; i++) {
        int s = tid + i * 512;
        int r = s >> 5, c8 = s & 31;
        const float* p = feat + (size_t)(m0 + r) * 256 + c8 * 8;
        const float4 f0 = *(const float4*)p;
        const float4 f1 = *(const float4*)(p + 4);
        *(bf16x8*)&As[r][c8 * 8] = pack8(f0, f1);
    }
    #pragma unroll
    for (int i = 0; i < 16; i++) {
        int s = tid + i * 512;
        int k = s >> 5, n4 = (s & 31) * 4;
        const float4 f = *(const float4*)(W + (size_t)k * 128 + n4);
        Bs[n4 + 0][k] = f2bf(f.x); Bs[n4 + 1][k] = f2bf(f.y);
        Bs[n4 + 2][k] = f2bf(f.z); Bs[n4 + 3][k] = f2bf(f.w);
    }
    __syncthreads();

    f32x4 acc[4];
    #pragma unroll
    for (int t = 0; t < 4; t++) acc[t] = f32x4{0.f, 0.f, 0.f, 0.f};
    #pragma unroll
    for (int ks = 0; ks < 8; ks++) {
        bf16x8 af = *(const bf16x8*)&As[wm * 16 + ln15][ks * 32 + quad * 8];
        #pragma unroll
        for (int t = 0; t < 4; t++) {
            bf16x8 bf = *(const bf16x8*)&Bs[wn * 64 + t * 16 + ln15][ks * 32 + quad * 8];
            acc[t] = __builtin_amdgcn_mfma_f32_16x16x32_bf16(af, bf, acc[t], 0, 0, 0);
        }
    }
    #pragma unroll
    for (int t = 0; t < 4; t++) {
        int n = wn * 64 + t * 16 + ln15;
        int mb = m0 + wm * 16 + quad * 4;
        if (mat == 2) {
            ushort4 w;
            w.x = f2bf(acc[t][0]); w.y = f2bf(acc[t][1]);
            w.z = f2bf(acc[t][2]); w.w = f2bf(acc[t][3]);
            *(ushort4*)(VbT + (size_t)n * 8192 + mb) = w;
        } else {
            unsigned short* dst = (mat == 0) ? Qb : Kb;
            #pragma unroll
            for (int reg = 0; reg < 4; reg++)
                dst[(size_t)(mb + reg) * 128 + n] = f2bf(acc[t][reg]);
        }
    }
    if (mat == 2) {
        #pragma unroll
        for (int i = 0; i < 8; i++) {
            int idx = tid + i * 512;
            int rr = idx >> 6, c = idx & 63;
            VbT[(size_t)(128 + rr) * 8192 + m0 + c] =
                (rr == 0) ? (unsigned short)0x3F80 : (unsigned short)0;
        }
    }
}

// ---------------------------------------------------------------------------
// Kernel 2: row norms of Q, global max row-norm^2 of K.
// ---------------------------------------------------------------------------
__global__ __launch_bounds__(128) void norms_kernel(
    const unsigned short* __restrict__ Qb, const unsigned short* __restrict__ Kb,
    float* __restrict__ qn2, unsigned* __restrict__ knmax) {
    const int r = blockIdx.x, j = threadIdx.x;
    float q = bf2f(Qb[(size_t)r * 128 + j]);
    float k = bf2f(Kb[(size_t)r * 128 + j]);
    float sq = q * q, sk = k * k;
    for (int m = 1; m < 64; m <<= 1) {
        sq += __shfl_xor(sq, m, 64);
        sk += __shfl_xor(sk, m, 64);
    }
    __shared__ float s0[2], s1[2];
    if ((j & 63) == 0) { s0[j >> 6] = sq; s1[j >> 6] = sk; }
    __syncthreads();
    if (j == 0)  qn2[r] = s0[0] + s0[1];
    if (j == 64) atomicMax(knmax, __float_as_uint(s1[0] + s1[1]));
}

// ---------------------------------------------------------------------------
// Kernel 3: CVf32 += (C @ V_ext)^T partials.  M=128, ksplit 8 -> grid 512,
// (512,2) -> 128 VGPR cap, 2 blocks/CU.  Dist-2 reg prefetch.
// ---------------------------------------------------------------------------
__global__ __launch_bounds__(512, 2) void cv_kernel(
    const float* __restrict__ C, const unsigned short* __restrict__ VbT,
    float* __restrict__ CVf32) {
    __shared__ unsigned short As[128][72];   // 18 KB
    __shared__ unsigned short Bs[192][72];   // 27 KB  (45 KB -> 2 blocks/CU)
    const int tid = threadIdx.x;
    const int rg = blockIdx.x >> 3, sp = blockIdx.x & 7;
    const int m0 = rg * 128;
    const int k0 = sp * 1024;
    const int lane = tid & 63, wv = tid >> 6;
    const int p4 = wv & 3, h2 = wv >> 2;
    const int ln15 = lane & 15, quad = lane >> 4;

    const int ar = tid >> 3, ac8 = tid & 7;
    const float* Ab0 = C + (size_t)(m0 + ar) * 8192 + k0 + ac8 * 8;
    const float* Ab1 = Ab0 + (size_t)64 * 8192;

    float4 pa[2][4];
    bf16x8 pb[2][3];
    #pragma unroll
    for (int d = 0; d < 2; d++) {
        const int kb = d * 64;
        pa[d][0] = *(const float4*)(Ab0 + kb); pa[d][1] = *(const float4*)(Ab0 + kb + 4);
        pa[d][2] = *(const float4*)(Ab1 + kb); pa[d][3] = *(const float4*)(Ab1 + kb + 4);
        #pragma unroll
        for (int i = 0; i < 3; i++) {
            int s = tid + i * 512;
            pb[d][i] = *(const bf16x8*)(VbT + (size_t)(s >> 3) * 8192 + k0 + kb + (s & 7) * 8);
        }
    }

    f32x4 acc[2][5];
    #pragma unroll
    for (int mt = 0; mt < 2; mt++)
        #pragma unroll
        for (int t = 0; t < 5; t++) acc[mt][t] = f32x4{0.f, 0.f, 0.f, 0.f};

    for (int c = 0; c < 16; c += 2) {
        #pragma unroll
        for (int d = 0; d < 2; d++) {
            __syncthreads();
            *(bf16x8*)&As[ar][ac8 * 8]      = pack8(pa[d][0], pa[d][1]);
            *(bf16x8*)&As[ar + 64][ac8 * 8] = pack8(pa[d][2], pa[d][3]);
            #pragma unroll
            for (int i = 0; i < 3; i++) {
                int s = tid + i * 512;
                *(bf16x8*)&Bs[s >> 3][(s & 7) * 8] = pb[d][i];
            }
            if (c + d + 2 < 16) {
                const int kb = (c + d + 2) * 64;
                pa[d][0] = *(const float4*)(Ab0 + kb); pa[d][1] = *(const float4*)(Ab0 + kb + 4);
                pa[d][2] = *(const float4*)(Ab1 + kb); pa[d][3] = *(const float4*)(Ab1 + kb + 4);
                #pragma unroll
                for (int i = 0; i < 3; i++) {
                    int s = tid + i * 512;
                    pb[d][i] = *(const bf16x8*)(VbT + (size_t)(s >> 3) * 8192 + k0 + kb + (s & 7) * 8);
                }
            }
            __syncthreads();
            #pragma unroll
            for (int k2 = 0; k2 < 2; k2++) {
                bf16x8 a0 = *(const bf16x8*)&As[p4 * 32 + ln15][k2 * 32 + quad * 8];
                bf16x8 a1 = *(const bf16x8*)&As[p4 * 32 + 16 + ln15][k2 * 32 + quad * 8];
                #pragma unroll
                for (int t = 0; t < 5; t++) {
                    bf16x8 bf = *(const bf16x8*)&Bs[h2 * 80 + t * 16 + ln15][k2 * 32 + quad * 8];
                    acc[0][t] = __builtin_amdgcn_mfma_f32_16x16x32_bf16(a0, bf, acc[0][t], 0, 0, 0);
                    acc[1][t] = __builtin_amdgcn_mfma_f32_16x16x32_bf16(a1, bf, acc[1][t], 0, 0, 0);
                }
            }
        }
    }
    #pragma unroll
    for (int mt = 0; mt < 2; mt++)
        #pragma unroll
        for (int t = 0; t < 5; t++) {
            int n = h2 * 80 + t * 16 + ln15;
            int mb = m0 + p4 * 32 + mt * 16 + quad * 4;
            #pragma unroll
            for (int reg = 0; reg < 4; reg++)
                atomicAdd(&CVf32[(size_t)n * 8192 + mb + reg], acc[mt][t][reg]);
        }
}

// ---------------------------------------------------------------------------
// Kernel 3b: CVbT bf16 = CVf32 (rows 0..159).
// ---------------------------------------------------------------------------
__global__ __launch_bounds__(256) void cvt_kernel(
    const float* __restrict__ CVf32, unsigned short* __restrict__ CVbT) {
    int idx = blockIdx.x * 256 + threadIdx.x;
    const float* p = CVf32 + (size_t)idx * 8;
    const float4 f0 = *(const float4*)p;
    const float4 f1 = *(const float4*)(p + 4);
    *(bf16x8*)(CVbT + (size_t)idx * 8) = pack8(f0, f1);
}

// ---------------------------------------------------------------------------
// Kernel 4 v4: Q-fragments in REGISTERS (32 VGPR/wave), no Qs LDS.
// LDS = Ks 17 KB + Cs 22.5 KB + Ps 17 KB = 56.5 KB -> 2 blocks/CU with (512,2).
// ---------------------------------------------------------------------------
__global__ __launch_bounds__(512, 2) void flash_kernel(
    const unsigned short* __restrict__ Qb, const unsigned short* __restrict__ Kb,
    const unsigned short* __restrict__ CVbT, const float* __restrict__ qn2,
    const unsigned* __restrict__ knmax, float* __restrict__ Of32) {
    __shared__ unsigned short Ks[64][136];   // 17 KB
    __shared__ unsigned short Cs[160][72];   // 22.5 KB
    __shared__ unsigned short Ps[128][68];   // 17 KB (stride 68: conflict-free writes)
    const int tid = threadIdx.x;
    const int rg = blockIdx.x >> 3, sp = blockIdx.x & 7;
    const int i0 = rg * 128;
    const int k0 = sp * 1024;
    const int lane = tid & 63, wv = tid >> 6;
    const int ln15 = lane & 15, quad = lane >> 4;
    const int p4 = wv & 3;    // m-pair: rows 32*p4..+32
    const int h2 = wv >> 2;   // QK: key-half; PV: n-half

    // Q A-fragments in registers: wave only needs its own 32 rows.
    // A layout (16x16x32): lane ln15 = m, quad*8+j = k within 32-chunk kk.
    bf16x8 qf[2][4];
    #pragma unroll
    for (int mt = 0; mt < 2; mt++)
        #pragma unroll
        for (int kk = 0; kk < 4; kk++) {
            int row = i0 + p4 * 32 + mt * 16 + ln15;
            qf[mt][kk] = *(const bf16x8*)(Qb + (size_t)row * 128 + kk * 32 + quad * 8);
        }
    const float kn2 = __uint_as_float(*knmax);
    float Msr[2][4];
    #pragma unroll
    for (int mt = 0; mt < 2; mt++)
        #pragma unroll
        for (int reg = 0; reg < 4; reg++) {
            int row = p4 * 32 + mt * 16 + quad * 4 + reg;
            Msr[mt][reg] = sqrtf(qn2[i0 + row] * kn2) * SCALE;
        }

    bf16x8 pkK[2], pkC[3];
    {
        const int kb = k0;
        #pragma unroll
        for (int i = 0; i < 2; i++) {
            int s = tid + i * 512;
            pkK[i] = *(const bf16x8*)(Kb + (size_t)(kb + (s >> 4)) * 128 + (s & 15) * 8);
        }
        #pragma unroll
        for (int i = 0; i < 3; i++) {
            int s = tid + i * 512;
            if (s < 1280)
                pkC[i] = *(const bf16x8*)(CVbT + (size_t)(s >> 3) * 8192 + kb + (s & 7) * 8);
        }
    }

    f32x4 acc[2][5];
    #pragma unroll
    for (int mt = 0; mt < 2; mt++)
        #pragma unroll
        for (int t = 0; t < 5; t++) acc[mt][t] = f32x4{0.f, 0.f, 0.f, 0.f};

    for (int c = 0; c < 16; c++) {
        __syncthreads();
        #pragma unroll
        for (int i = 0; i < 2; i++) {
            int s = tid + i * 512;
            *(bf16x8*)&Ks[s >> 4][(s & 15) * 8] = pkK[i];
        }
        #pragma unroll
        for (int i = 0; i < 3; i++) {
            int s = tid + i * 512;
            if (s < 1280) *(bf16x8*)&Cs[s >> 3][(s & 7) * 8] = pkC[i];
        }
        if (c + 1 < 16) {
            const int kb = k0 + (c + 1) * 64;
            #pragma unroll
            for (int i = 0; i < 2; i++) {
                int s = tid + i * 512;
                pkK[i] = *(const bf16x8*)(Kb + (size_t)(kb + (s >> 4)) * 128 + (s & 15) * 8);
            }
            #pragma unroll
            for (int i = 0; i < 3; i++) {
                int s = tid + i * 512;
                if (s < 1280)
                    pkC[i] = *(const bf16x8*)(CVbT + (size_t)(s >> 3) * 8192 + kb + (s & 7) * 8);
            }
        }
        __syncthreads();

        // QK: rows 32*p4..+32 x keys 32*h2..+32
        f32x4 pacc[2][2];
        #pragma unroll
        for (int mt = 0; mt < 2; mt++)
            #pragma unroll
            for (int kt = 0; kt < 2; kt++) pacc[mt][kt] = f32x4{0.f, 0.f, 0.f, 0.f};
        #pragma unroll
        for (int kk = 0; kk < 4; kk++) {
            #pragma unroll
            for (int kt = 0; kt < 2; kt++) {
                bf16x8 bk = *(const bf16x8*)&Ks[h2 * 32 + kt * 16 + ln15][kk * 32 + quad * 8];
                pacc[0][kt] = __builtin_amdgcn_mfma_f32_16x16x32_bf16(qf[0][kk], bk, pacc[0][kt], 0, 0, 0);
                pacc[1][kt] = __builtin_amdgcn_mfma_f32_16x16x32_bf16(qf[1][kk], bk, pacc[1][kt], 0, 0, 0);
            }
        }
        #pragma unroll
        for (int mt = 0; mt < 2; mt++)
            #pragma unroll
            for (int kt = 0; kt < 2; kt++)
                #pragma unroll
                for (int reg = 0; reg < 4; reg++) {
                    int row = p4 * 32 + mt * 16 + quad * 4 + reg;
                    int key = h2 * 32 + kt * 16 + ln15;
                    float p = __expf(pacc[mt][kt][reg] * SCALE - Msr[mt][reg]);
                    Ps[row][key] = f2bf(p);
                }
        __syncthreads();

        // PV: rows 32*p4..+32 x n = 80*h2..+80 (Ps read as 8B-aligned b64 pairs)
        #pragma unroll
        for (int ks = 0; ks < 2; ks++) {
            bf16x4 lo0 = *(const bf16x4*)&Ps[p4 * 32 + ln15][ks * 32 + quad * 8];
            bf16x4 hi0 = *(const bf16x4*)&Ps[p4 * 32 + ln15][ks * 32 + quad * 8 + 4];
            bf16x4 lo1 = *(const bf16x4*)&Ps[p4 * 32 + 16 + ln15][ks * 32 + quad * 8];
            bf16x4 hi1 = *(const bf16x4*)&Ps[p4 * 32 + 16 + ln15][ks * 32 + quad * 8 + 4];
            bf16x8 ap0, ap1;
            #pragma unroll
            for (int j = 0; j < 4; j++) {
                ap0[j] = lo0[j]; ap0[j + 4] = hi0[j];
                ap1[j] = lo1[j]; ap1[j + 4] = hi1[j];
            }
            #pragma unroll
            for (int t = 0; t < 5; t++) {
                bf16x8 bc = *(const bf16x8*)&Cs[h2 * 80 + t * 16 + ln15][ks * 32 + quad * 8];
                acc[0][t] = __builtin_amdgcn_mfma_f32_16x16x32_bf16(ap0, bc, acc[0][t], 0, 0, 0);
                acc[1][t] = __builtin_amdgcn_mfma_f32_16x16x32_bf16(ap1, bc, acc[1][t], 0, 0, 0);
            }
        }
    }
    #pragma unroll
    for (int mt = 0; mt < 2; mt++)
        #pragma unroll
        for (int t = 0; t < 5; t++)
            #pragma unroll
            for (int reg = 0; reg < 4; reg++) {
                int row = i0 + p4 * 32 + mt * 16 + quad * 4 + reg;
                int n = h2 * 80 + t * 16 + ln15;
                atomicAdd(&Of32[(size_t)row * 160 + n], acc[mt][t][reg]);
            }
}

// ---------------------------------------------------------------------------
// Kernel 5: out = elu(O / (deno + 1e-9)), deno = column 128 of Of32.
// ---------------------------------------------------------------------------
__global__ __launch_bounds__(256) void finalize_kernel(
    const float* __restrict__ Of32, float* __restrict__ out) {
    int idx = blockIdx.x * 256 + threadIdx.x;
    int i = idx >> 7, n = idx & 127;
    float deno = Of32[(size_t)i * 160 + 128] + 1e-9f;
    float v = Of32[(size_t)i * 160 + n] / deno;
    out[idx] = (v > 0.f) ? v : expm1f(v);
}

// ---------------------------------------------------------------------------
extern "C" void kernel_launch(void* const* d_in, const int* in_sizes, int n_in,
                              void* d_out, int out_size, void* d_ws, size_t ws_size,
                              hipStream_t stream) {
    const float* feat = (const float*)d_in[0];
    // d_in[1] = bg (unused scalar)
    const float* C    = (const float*)d_in[2];
    const float* Wq   = (const float*)d_in[3];
    const float* Wk   = (const float*)d_in[4];
    const float* Wv   = (const float*)d_in[5];
    float* out = (float*)d_out;

    char* ws = (char*)d_ws;
    unsigned short* Qb   = (unsigned short*)(ws + 0);          // 2 MB
    unsigned short* Kb   = (unsigned short*)(ws + 2097152);    // 2 MB
    unsigned short* VbT  = (unsigned short*)(ws + 4194304);    // 192x8192x2 = 3 MB
    float*          CVf32= (float*)(ws + 7340032);             // 160x8192x4 = 5.25 MB
    unsigned short* CVbT = (unsigned short*)(ws + 12845056);   // 192x8192x2 = 3 MB
    float*          Of32 = (float*)(ws + 15990784);            // 8192x160x4 = 5.25 MB
    float*          qn2  = (float*)(ws + 21495808);            // 32 KB
    unsigned*       knmax= (unsigned*)(ws + 21528576);         // 4 B

    hipMemsetAsync(knmax, 0, 4, stream);
    hipMemsetAsync(CVf32, 0, 160 * 8192 * sizeof(float), stream);
    hipMemsetAsync(Of32, 0, 8192 * 160 * sizeof(float), stream);
    qkv_mfma<<<dim3(128, 3), 512, 0, stream>>>(feat, Wq, Wk, Wv, Qb, Kb, VbT);
    norms_kernel<<<8192, 128, 0, stream>>>(Qb, Kb, qn2, knmax);
    cv_kernel<<<512, 512, 0, stream>>>(C, VbT, CVf32);
    cvt_kernel<<<640, 256, 0, stream>>>(CVf32, CVbT);
    flash_kernel<<<512, 512, 0, stream>>>(Qb, Kb, CVbT, qn2, knmax, Of32);
    finalize_kernel<<<4096, 256, 0, stream>>>(Of32, out);
}

// Round 5
// 666.796 us; speedup vs baseline: 1.1285x; 1.0627x over previous
//
#include <hip/hip_runtime.h>

// GKAT layer, restructured:
//   ret = elu( (S @ (C @ V_ext)) / (S @ rowsum(C) + eps) )
// where S = exp(scale*Q@K^T - M_i), M_i = ||Q_i|| * max_j ||K_j|| * scale
// (Cauchy-Schwarz upper bound on rowmax; exact rowmax cancels in the ratio).
// V_ext = [V | ones | pad] so rowsum(C) rides as column 128 of C@V_ext.
//
// R5: cv rebuilt m97-style: C pre-converted to bf16 (streaming pass), K-loop
// stages A and B via global_load_lds width=16 (async DMA, no VGPR round trip),
// XOR-swizzled unpadded LDS tiles (DMA-contiguous AND conflict-free reads),
// no atomics (4 disjoint fp32 partial buffers + reduce). Small reg footprint
// -> ~5 blocks/CU co-resident (R3/R4 failed on register-driven occupancy
// collapse: 88 arch + 40 AGPR unified-file -> ~1 block/CU).

#define SCALE 0.088388347648318447f   // 1/sqrt(128)

typedef __attribute__((ext_vector_type(8))) short bf16x8;   // 8 bf16 (4 VGPRs)
typedef __attribute__((ext_vector_type(4))) short bf16x4;   // 8-byte LDS loads
typedef __attribute__((ext_vector_type(4))) float f32x4;

static __device__ __forceinline__ unsigned short f2bf(float f) {
    unsigned u = __float_as_uint(f);
    u = (u + 0x7fffu + ((u >> 16) & 1u)) >> 16;   // RNE
    return (unsigned short)u;
}
static __device__ __forceinline__ float bf2f(unsigned short b) {
    return __uint_as_float(((unsigned)b) << 16);
}
static __device__ __forceinline__ bf16x8 pack8(const float4& a, const float4& b) {
    bf16x8 v;
    v[0] = (short)f2bf(a.x); v[1] = (short)f2bf(a.y);
    v[2] = (short)f2bf(a.z); v[3] = (short)f2bf(a.w);
    v[4] = (short)f2bf(b.x); v[5] = (short)f2bf(b.y);
    v[6] = (short)f2bf(b.z); v[7] = (short)f2bf(b.w);
    return v;
}
// async global->LDS DMA, 16B per lane; LDS dest = base + lane*16
static __device__ __forceinline__ void gl_lds16(const unsigned short* g, unsigned short* l) {
    __builtin_amdgcn_global_load_lds(
        (const __attribute__((address_space(1))) unsigned int*)g,
        (__attribute__((address_space(3))) unsigned int*)l, 16, 0, 0);
}

// ---------------------------------------------------------------------------
// Kernel 0: Cbf = bf16(C).  Pure streaming, 384 MB moved.
// ---------------------------------------------------------------------------
__global__ __launch_bounds__(256) void c2bf_kernel(
    const float* __restrict__ C, unsigned short* __restrict__ Cbf) {
    const int tid0 = blockIdx.x * 256 + threadIdx.x;
    const int stride = 256 * 4096;               // 1,048,576 threads
    #pragma unroll
    for (int i = 0; i < 8; i++) {                // 8,388,608 slots of 8 elems
        size_t s = (size_t)(tid0 + i * stride) * 8;
        const float4 f0 = *(const float4*)(C + s);
        const float4 f1 = *(const float4*)(C + s + 4);
        *(bf16x8*)(Cbf + s) = pack8(f0, f1);
    }
}

// ---------------------------------------------------------------------------
// Kernel 1: one block = 64 feat rows x one full W matrix. Single barrier.
// ---------------------------------------------------------------------------
__global__ __launch_bounds__(512) void qkv_mfma(
    const float* __restrict__ feat, const float* __restrict__ Wq,
    const float* __restrict__ Wk, const float* __restrict__ Wv,
    unsigned short* __restrict__ Qb, unsigned short* __restrict__ Kb,
    unsigned short* __restrict__ VbT) {
    __shared__ unsigned short As[64][264];
    __shared__ unsigned short Bs[128][264];
    const int tid = threadIdx.x;
    const int m0 = blockIdx.x * 64;
    const int mat = blockIdx.y;
    const float* W = (mat == 0) ? Wq : (mat == 1) ? Wk : Wv;
    const int lane = tid & 63, wv = tid >> 6;
    const int wm = wv & 3, wn = wv >> 2;
    const int ln15 = lane & 15, quad = lane >> 4;

    #pragma unroll
    for (int i = 0; i < 4; i++) {
        int s = tid + i * 512;
        int r = s >> 5, c8 = s & 31;
        const float* p = feat + (size_t)(m0 + r) * 256 + c8 * 8;
        const float4 f0 = *(const float4*)p;
        const float4 f1 = *(const float4*)(p + 4);
        *(bf16x8*)&As[r][c8 * 8] = pack8(f0, f1);
    }
    #pragma unroll
    for (int i = 0; i < 16; i++) {
        int s = tid + i * 512;
        int k = s >> 5, n4 = (s & 31) * 4;
        const float4 f = *(const float4*)(W + (size_t)k * 128 + n4);
        Bs[n4 + 0][k] = f2bf(f.x); Bs[n4 + 1][k] = f2bf(f.y);
        Bs[n4 + 2][k] = f2bf(f.z); Bs[n4 + 3][k] = f2bf(f.w);
    }
    __syncthreads();

    f32x4 acc[4];
    #pragma unroll
    for (int t = 0; t < 4; t++) acc[t] = f32x4{0.f, 0.f, 0.f, 0.f};
    #pragma unroll
    for (int ks = 0; ks < 8; ks++) {
        bf16x8 af = *(const bf16x8*)&As[wm * 16 + ln15][ks * 32 + quad * 8];
        #pragma unroll
        for (int t = 0; t < 4; t++) {
            bf16x8 bf = *(const bf16x8*)&Bs[wn * 64 + t * 16 + ln15][ks * 32 + quad * 8];
            acc[t] = __builtin_amdgcn_mfma_f32_16x16x32_bf16(af, bf, acc[t], 0, 0, 0);
        }
    }
    #pragma unroll
    for (int t = 0; t < 4; t++) {
        int n = wn * 64 + t * 16 + ln15;
        int mb = m0 + wm * 16 + quad * 4;
        if (mat == 2) {
            ushort4 w;
            w.x = f2bf(acc[t][0]); w.y = f2bf(acc[t][1]);
            w.z = f2bf(acc[t][2]); w.w = f2bf(acc[t][3]);
            *(ushort4*)(VbT + (size_t)n * 8192 + mb) = w;
        } else {
            unsigned short* dst = (mat == 0) ? Qb : Kb;
            #pragma unroll
            for (int reg = 0; reg < 4; reg++)
                dst[(size_t)(mb + reg) * 128 + n] = f2bf(acc[t][reg]);
        }
    }
    if (mat == 2) {
        #pragma unroll
        for (int i = 0; i < 8; i++) {
            int idx = tid + i * 512;
            int rr = idx >> 6, c = idx & 63;
            VbT[(size_t)(128 + rr) * 8192 + m0 + c] =
                (rr == 0) ? (unsigned short)0x3F80 : (unsigned short)0;
        }
    }
}

// ---------------------------------------------------------------------------
// Kernel 2: row norms of Q, global max row-norm^2 of K.
// ---------------------------------------------------------------------------
__global__ __launch_bounds__(128) void norms_kernel(
    const unsigned short* __restrict__ Qb, const unsigned short* __restrict__ Kb,
    float* __restrict__ qn2, unsigned* __restrict__ knmax) {
    const int r = blockIdx.x, j = threadIdx.x;
    float q = bf2f(Qb[(size_t)r * 128 + j]);
    float k = bf2f(Kb[(size_t)r * 128 + j]);
    float sq = q * q, sk = k * k;
    for (int m = 1; m < 64; m <<= 1) {
        sq += __shfl_xor(sq, m, 64);
        sk += __shfl_xor(sk, m, 64);
    }
    __shared__ float s0[2], s1[2];
    if ((j & 63) == 0) { s0[j >> 6] = sq; s1[j >> 6] = sk; }
    __syncthreads();
    if (j == 0)  qn2[r] = s0[0] + s0[1];
    if (j == 64) atomicMax(knmax, __float_as_uint(s1[0] + s1[1]));
}

// ---------------------------------------------------------------------------
// Kernel 3 v5: CVpart[sp] = Cbf[m-range][k-range] @ V_ext^T.  M=64/block,
// ksplit 4 -> grid 512.  256 thr (4 waves: mh x h2).  A/B staged by
// global_load_lds 16B DMA into unpadded XOR-swizzled LDS tiles.
// Tiny reg footprint -> many co-resident blocks.  No atomics.
// ---------------------------------------------------------------------------
__global__ __launch_bounds__(256) void cv_kernel(
    const unsigned short* __restrict__ Cbf, const unsigned short* __restrict__ VbT,
    float* __restrict__ CVpart) {
    __shared__ unsigned short As[64 * 64];    // 8 KB, swizzled groups
    __shared__ unsigned short Bs[192 * 64];   // 24 KB, swizzled groups
    const int tid = threadIdx.x;
    const int rg = blockIdx.x >> 2, sp = blockIdx.x & 3;
    const int m0 = rg * 64;
    const int k0 = sp * 2048;                 // 32 chunks of 64
    const int lane = tid & 63, wv = tid >> 6;
    const int mh = wv & 1, h2 = wv >> 1;      // rows mh*32..+32, n-half 80*h2
    const int ln15 = lane & 15, quad = lane >> 4;

    f32x4 acc[2][5];
    #pragma unroll
    for (int mt = 0; mt < 2; mt++)
        #pragma unroll
        for (int t = 0; t < 5; t++) acc[mt][t] = f32x4{0.f, 0.f, 0.f, 0.f};

    // precompute swizzled read offsets (row&7 == ln15&7 since bases are x8)
    const int ra0 = mh * 32 + ln15;          // A rows for mt=0 / mt=1
    const int ra1 = mh * 32 + 16 + ln15;

    for (int c = 0; c < 32; c++) {
        const int kb = k0 + c * 64;
        __syncthreads();   // previous chunk's ds_reads done
        // A DMA: 8 wave-instrs cover 64 rows x 8 groups (512 slots)
        #pragma unroll
        for (int i = 0; i < 2; i++) {
            int s = (i * 4 + wv) * 64 + lane;
            int r = s >> 3, g = (s & 7) ^ (r & 7);
            gl_lds16(Cbf + (size_t)(m0 + r) * 8192 + kb + g * 8,
                     &As[(i * 4 + wv) * 512]);
        }
        // B DMA: 24 wave-instrs cover 192 rows x 8 groups (1536 slots)
        #pragma unroll
        for (int i = 0; i < 6; i++) {
            int s = (i * 4 + wv) * 64 + lane;
            int r = s >> 3, g = (s & 7) ^ (r & 7);
            gl_lds16(VbT + (size_t)r * 8192 + kb + g * 8,
                     &Bs[(i * 4 + wv) * 512]);
        }
        __syncthreads();   // implicit vmcnt(0) drain completes the DMA
        #pragma unroll
        for (int k2 = 0; k2 < 2; k2++) {
            const int lg = k2 * 4 + quad;
            bf16x8 a0 = *(const bf16x8*)&As[ra0 * 64 + ((lg ^ (ra0 & 7)) * 8)];
            bf16x8 a1 = *(const bf16x8*)&As[ra1 * 64 + ((lg ^ (ra1 & 7)) * 8)];
            #pragma unroll
            for (int t = 0; t < 5; t++) {
                int n = h2 * 80 + t * 16 + ln15;
                bf16x8 bf = *(const bf16x8*)&Bs[n * 64 + ((lg ^ (n & 7)) * 8)];
                acc[0][t] = __builtin_amdgcn_mfma_f32_16x16x32_bf16(a0, bf, acc[0][t], 0, 0, 0);
                acc[1][t] = __builtin_amdgcn_mfma_f32_16x16x32_bf16(a1, bf, acc[1][t], 0, 0, 0);
            }
        }
    }
    // store partials: CVpart[sp][n][m], plain float4 stores (no atomics)
    float* dst = CVpart + (size_t)sp * 160 * 8192;
    #pragma unroll
    for (int mt = 0; mt < 2; mt++)
        #pragma unroll
        for (int t = 0; t < 5; t++) {
            int n = h2 * 80 + t * 16 + ln15;
            int m = m0 + mh * 32 + mt * 16 + quad * 4;
            float4 w;
            w.x = acc[mt][t][0]; w.y = acc[mt][t][1];
            w.z = acc[mt][t][2]; w.w = acc[mt][t][3];
            *(float4*)(dst + (size_t)n * 8192 + m) = w;
        }
}

// ---------------------------------------------------------------------------
// Kernel 3b: CVbT bf16 = sum of 4 partials.
// ---------------------------------------------------------------------------
__global__ __launch_bounds__(256) void cvreduce_kernel(
    const float* __restrict__ CVpart, unsigned short* __restrict__ CVbT) {
    const size_t STR = (size_t)160 * 8192;
    int idx = blockIdx.x * 256 + threadIdx.x;    // 327680 float4-slots
    const float* p = CVpart + (size_t)idx * 4;
    float4 s = *(const float4*)p;
    #pragma unroll
    for (int j = 1; j < 4; j++) {
        const float4 q = *(const float4*)(p + j * STR);
        s.x += q.x; s.y += q.y; s.z += q.z; s.w += q.w;
    }
    ushort4 w;
    w.x = f2bf(s.x); w.y = f2bf(s.y); w.z = f2bf(s.z); w.w = f2bf(s.w);
    *(ushort4*)(CVbT + (size_t)idx * 4) = w;
}

// ---------------------------------------------------------------------------
// Kernel 4: flash (unchanged from R4, passing).  Q-frags in registers.
// ---------------------------------------------------------------------------
__global__ __launch_bounds__(512, 2) void flash_kernel(
    const unsigned short* __restrict__ Qb, const unsigned short* __restrict__ Kb,
    const unsigned short* __restrict__ CVbT, const float* __restrict__ qn2,
    const unsigned* __restrict__ knmax, float* __restrict__ Of32) {
    __shared__ unsigned short Ks[64][136];   // 17 KB
    __shared__ unsigned short Cs[160][72];   // 22.5 KB
    __shared__ unsigned short Ps[128][68];   // 17 KB
    const int tid = threadIdx.x;
    const int rg = blockIdx.x >> 3, sp = blockIdx.x & 7;
    const int i0 = rg * 128;
    const int k0 = sp * 1024;
    const int lane = tid & 63, wv = tid >> 6;
    const int ln15 = lane & 15, quad = lane >> 4;
    const int p4 = wv & 3;
    const int h2 = wv >> 2;

    bf16x8 qf[2][4];
    #pragma unroll
    for (int mt = 0; mt < 2; mt++)
        #pragma unroll
        for (int kk = 0; kk < 4; kk++) {
            int row = i0 + p4 * 32 + mt * 16 + ln15;
            qf[mt][kk] = *(const bf16x8*)(Qb + (size_t)row * 128 + kk * 32 + quad * 8);
        }
    const float kn2 = __uint_as_float(*knmax);
    float Msr[2][4];
    #pragma unroll
    for (int mt = 0; mt < 2; mt++)
        #pragma unroll
        for (int reg = 0; reg < 4; reg++) {
            int row = p4 * 32 + mt * 16 + quad * 4 + reg;
            Msr[mt][reg] = sqrtf(qn2[i0 + row] * kn2) * SCALE;
        }

    bf16x8 pkK[2], pkC[3];
    {
        const int kb = k0;
        #pragma unroll
        for (int i = 0; i < 2; i++) {
            int s = tid + i * 512;
            pkK[i] = *(const bf16x8*)(Kb + (size_t)(kb + (s >> 4)) * 128 + (s & 15) * 8);
        }
        #pragma unroll
        for (int i = 0; i < 3; i++) {
            int s = tid + i * 512;
            if (s < 1280)
                pkC[i] = *(const bf16x8*)(CVbT + (size_t)(s >> 3) * 8192 + kb + (s & 7) * 8);
        }
    }

    f32x4 acc[2][5];
    #pragma unroll
    for (int mt = 0; mt < 2; mt++)
        #pragma unroll
        for (int t = 0; t < 5; t++) acc[mt][t] = f32x4{0.f, 0.f, 0.f, 0.f};

    for (int c = 0; c < 16; c++) {
        __syncthreads();
        #pragma unroll
        for (int i = 0; i < 2; i++) {
            int s = tid + i * 512;
            *(bf16x8*)&Ks[s >> 4][(s & 15) * 8] = pkK[i];
        }
        #pragma unroll
        for (int i = 0; i < 3; i++) {
            int s = tid + i * 512;
            if (s < 1280) *(bf16x8*)&Cs[s >> 3][(s & 7) * 8] = pkC[i];
        }
        if (c + 1 < 16) {
            const int kb = k0 + (c + 1) * 64;
            #pragma unroll
            for (int i = 0; i < 2; i++) {
                int s = tid + i * 512;
                pkK[i] = *(const bf16x8*)(Kb + (size_t)(kb + (s >> 4)) * 128 + (s & 15) * 8);
            }
            #pragma unroll
            for (int i = 0; i < 3; i++) {
                int s = tid + i * 512;
                if (s < 1280)
                    pkC[i] = *(const bf16x8*)(CVbT + (size_t)(s >> 3) * 8192 + kb + (s & 7) * 8);
            }
        }
        __syncthreads();

        f32x4 pacc[2][2];
        #pragma unroll
        for (int mt = 0; mt < 2; mt++)
            #pragma unroll
            for (int kt = 0; kt < 2; kt++) pacc[mt][kt] = f32x4{0.f, 0.f, 0.f, 0.f};
        #pragma unroll
        for (int kk = 0; kk < 4; kk++) {
            #pragma unroll
            for (int kt = 0; kt < 2; kt++) {
                bf16x8 bk = *(const bf16x8*)&Ks[h2 * 32 + kt * 16 + ln15][kk * 32 + quad * 8];
                pacc[0][kt] = __builtin_amdgcn_mfma_f32_16x16x32_bf16(qf[0][kk], bk, pacc[0][kt], 0, 0, 0);
                pacc[1][kt] = __builtin_amdgcn_mfma_f32_16x16x32_bf16(qf[1][kk], bk, pacc[1][kt], 0, 0, 0);
            }
        }
        #pragma unroll
        for (int mt = 0; mt < 2; mt++)
            #pragma unroll
            for (int kt = 0; kt < 2; kt++)
                #pragma unroll
                for (int reg = 0; reg < 4; reg++) {
                    int row = p4 * 32 + mt * 16 + quad * 4 + reg;
                    int key = h2 * 32 + kt * 16 + ln15;
                    float p = __expf(pacc[mt][kt][reg] * SCALE - Msr[mt][reg]);
                    Ps[row][key] = f2bf(p);
                }
        __syncthreads();

        #pragma unroll
        for (int ks = 0; ks < 2; ks++) {
            bf16x4 lo0 = *(const bf16x4*)&Ps[p4 * 32 + ln15][ks * 32 + quad * 8];
            bf16x4 hi0 = *(const bf16x4*)&Ps[p4 * 32 + ln15][ks * 32 + quad * 8 + 4];
            bf16x4 lo1 = *(const bf16x4*)&Ps[p4 * 32 + 16 + ln15][ks * 32 + quad * 8];
            bf16x4 hi1 = *(const bf16x4*)&Ps[p4 * 32 + 16 + ln15][ks * 32 + quad * 8 + 4];
            bf16x8 ap0, ap1;
            #pragma unroll
            for (int j = 0; j < 4; j++) {
                ap0[j] = lo0[j]; ap0[j + 4] = hi0[j];
                ap1[j] = lo1[j]; ap1[j + 4] = hi1[j];
            }
            #pragma unroll
            for (int t = 0; t < 5; t++) {
                bf16x8 bc = *(const bf16x8*)&Cs[h2 * 80 + t * 16 + ln15][ks * 32 + quad * 8];
                acc[0][t] = __builtin_amdgcn_mfma_f32_16x16x32_bf16(ap0, bc, acc[0][t], 0, 0, 0);
                acc[1][t] = __builtin_amdgcn_mfma_f32_16x16x32_bf16(ap1, bc, acc[1][t], 0, 0, 0);
            }
        }
    }
    #pragma unroll
    for (int mt = 0; mt < 2; mt++)
        #pragma unroll
        for (int t = 0; t < 5; t++)
            #pragma unroll
            for (int reg = 0; reg < 4; reg++) {
                int row = i0 + p4 * 32 + mt * 16 + quad * 4 + reg;
                int n = h2 * 80 + t * 16 + ln15;
                atomicAdd(&Of32[(size_t)row * 160 + n], acc[mt][t][reg]);
            }
}

// ---------------------------------------------------------------------------
// Kernel 5: out = elu(O / (deno + 1e-9)), deno = column 128 of Of32.
// ---------------------------------------------------------------------------
__global__ __launch_bounds__(256) void finalize_kernel(
    const float* __restrict__ Of32, float* __restrict__ out) {
    int idx = blockIdx.x * 256 + threadIdx.x;
    int i = idx >> 7, n = idx & 127;
    float deno = Of32[(size_t)i * 160 + 128] + 1e-9f;
    float v = Of32[(size_t)i * 160 + n] / deno;
    out[idx] = (v > 0.f) ? v : expm1f(v);
}

// ---------------------------------------------------------------------------
extern "C" void kernel_launch(void* const* d_in, const int* in_sizes, int n_in,
                              void* d_out, int out_size, void* d_ws, size_t ws_size,
                              hipStream_t stream) {
    const float* feat = (const float*)d_in[0];
    // d_in[1] = bg (unused scalar)
    const float* C    = (const float*)d_in[2];
    const float* Wq   = (const float*)d_in[3];
    const float* Wk   = (const float*)d_in[4];
    const float* Wv   = (const float*)d_in[5];
    float* out = (float*)d_out;

    char* ws = (char*)d_ws;
    unsigned short* Qb    = (unsigned short*)(ws + 0);           // 2 MB
    unsigned short* Kb    = (unsigned short*)(ws + 2097152);     // 2 MB
    unsigned short* VbT   = (unsigned short*)(ws + 4194304);     // 192x8192x2 = 3 MB
    unsigned short* Cbf   = (unsigned short*)(ws + 7340032);     // 8192x8192x2 = 128 MB
    float*          CVpart= (float*)(ws + 141557760);            // 4x160x8192x4 = 20 MB
    unsigned short* CVbT  = (unsigned short*)(ws + 162529280);   // 160x8192x2 = 2.5 MB
    float*          Of32  = (float*)(ws + 165150720);            // 8192x160x4 = 5.25 MB
    float*          qn2   = (float*)(ws + 170393600);            // 32 KB
    unsigned*       knmax = (unsigned*)(ws + 170426368);         // 4 B (~170.4 MB total)

    hipMemsetAsync(knmax, 0, 4, stream);
    hipMemsetAsync(Of32, 0, 8192 * 160 * sizeof(float), stream);
    c2bf_kernel<<<4096, 256, 0, stream>>>(C, Cbf);
    qkv_mfma<<<dim3(128, 3), 512, 0, stream>>>(feat, Wq, Wk, Wv, Qb, Kb, VbT);
    norms_kernel<<<8192, 128, 0, stream>>>(Qb, Kb, qn2, knmax);
    cv_kernel<<<512, 256, 0, stream>>>(Cbf, VbT, CVpart);
    cvreduce_kernel<<<1280, 256, 0, stream>>>(CVpart, CVbT);
    flash_kernel<<<512, 512, 0, stream>>>(Qb, Kb, CVbT, qn2, knmax, Of32);
    finalize_kernel<<<4096, 256, 0, stream>>>(Of32, out);
}

// Round 6
// 584.268 us; speedup vs baseline: 1.2879x; 1.1413x over previous
//
#include <hip/hip_runtime.h>

// GKAT layer, restructured:
//   ret = elu( (S @ (C @ V_ext)) / (S @ rowsum(C) + eps) )
// where S = exp(scale*Q@K^T - M_i), M_i = ||Q_i|| * max_j ||K_j|| * scale
// (Cauchy-Schwarz upper bound on rowmax; exact rowmax cancels in the ratio).
// V_ext = [V | ones | pad] so rowsum(C) rides as column 128 of C@V_ext.
//
// R6: flash rebuilt on cv-v5's DMA recipe (256thr, M=64, ksplit8, grid 1024,
// global_load_lds 16B into XOR-swizzled unpadded tiles, disjoint fp32
// partials instead of atomics). cv drops the c2bf prepass: A-tiles read
// fp32 C directly (each element read exactly once) with dist-1 reg
// prefetch; B stays DMA. Saves 256 MB of streaming + removes 2 dispatches.

#define SCALE 0.088388347648318447f   // 1/sqrt(128)

typedef __attribute__((ext_vector_type(8))) short bf16x8;   // 8 bf16 (4 VGPRs)
typedef __attribute__((ext_vector_type(4))) short bf16x4;   // 8-byte LDS loads
typedef __attribute__((ext_vector_type(4))) float f32x4;

static __device__ __forceinline__ unsigned short f2bf(float f) {
    unsigned u = __float_as_uint(f);
    u = (u + 0x7fffu + ((u >> 16) & 1u)) >> 16;   // RNE
    return (unsigned short)u;
}
static __device__ __forceinline__ float bf2f(unsigned short b) {
    return __uint_as_float(((unsigned)b) << 16);
}
static __device__ __forceinline__ bf16x8 pack8(const float4& a, const float4& b) {
    bf16x8 v;
    v[0] = (short)f2bf(a.x); v[1] = (short)f2bf(a.y);
    v[2] = (short)f2bf(a.z); v[3] = (short)f2bf(a.w);
    v[4] = (short)f2bf(b.x); v[5] = (short)f2bf(b.y);
    v[6] = (short)f2bf(b.z); v[7] = (short)f2bf(b.w);
    return v;
}
// async global->LDS DMA, 16B/lane; LDS dest = wave-uniform base + lane*16
static __device__ __forceinline__ void gl_lds16(const unsigned short* g, unsigned short* l) {
    __builtin_amdgcn_global_load_lds(
        (const __attribute__((address_space(1))) unsigned int*)g,
        (__attribute__((address_space(3))) unsigned int*)l, 16, 0, 0);
}

// ---------------------------------------------------------------------------
// Kernel 1: one block = 64 feat rows x one full W matrix. Single barrier.
// ---------------------------------------------------------------------------
__global__ __launch_bounds__(512) void qkv_mfma(
    const float* __restrict__ feat, const float* __restrict__ Wq,
    const float* __restrict__ Wk, const float* __restrict__ Wv,
    unsigned short* __restrict__ Qb, unsigned short* __restrict__ Kb,
    unsigned short* __restrict__ VbT) {
    __shared__ unsigned short As[64][264];
    __shared__ unsigned short Bs[128][264];
    const int tid = threadIdx.x;
    const int m0 = blockIdx.x * 64;
    const int mat = blockIdx.y;
    const float* W = (mat == 0) ? Wq : (mat == 1) ? Wk : Wv;
    const int lane = tid & 63, wv = tid >> 6;
    const int wm = wv & 3, wn = wv >> 2;
    const int ln15 = lane & 15, quad = lane >> 4;

    #pragma unroll
    for (int i = 0; i < 4; i++) {
        int s = tid + i * 512;
        int r = s >> 5, c8 = s & 31;
        const float* p = feat + (size_t)(m0 + r) * 256 + c8 * 8;
        const float4 f0 = *(const float4*)p;
        const float4 f1 = *(const float4*)(p + 4);
        *(bf16x8*)&As[r][c8 * 8] = pack8(f0, f1);
    }
    #pragma unroll
    for (int i = 0; i < 16; i++) {
        int s = tid + i * 512;
        int k = s >> 5, n4 = (s & 31) * 4;
        const float4 f = *(const float4*)(W + (size_t)k * 128 + n4);
        Bs[n4 + 0][k] = f2bf(f.x); Bs[n4 + 1][k] = f2bf(f.y);
        Bs[n4 + 2][k] = f2bf(f.z); Bs[n4 + 3][k] = f2bf(f.w);
    }
    __syncthreads();

    f32x4 acc[4];
    #pragma unroll
    for (int t = 0; t < 4; t++) acc[t] = f32x4{0.f, 0.f, 0.f, 0.f};
    #pragma unroll
    for (int ks = 0; ks < 8; ks++) {
        bf16x8 af = *(const bf16x8*)&As[wm * 16 + ln15][ks * 32 + quad * 8];
        #pragma unroll
        for (int t = 0; t < 4; t++) {
            bf16x8 bf = *(const bf16x8*)&Bs[wn * 64 + t * 16 + ln15][ks * 32 + quad * 8];
            acc[t] = __builtin_amdgcn_mfma_f32_16x16x32_bf16(af, bf, acc[t], 0, 0, 0);
        }
    }
    #pragma unroll
    for (int t = 0; t < 4; t++) {
        int n = wn * 64 + t * 16 + ln15;
        int mb = m0 + wm * 16 + quad * 4;
        if (mat == 2) {
            ushort4 w;
            w.x = f2bf(acc[t][0]); w.y = f2bf(acc[t][1]);
            w.z = f2bf(acc[t][2]); w.w = f2bf(acc[t][3]);
            *(ushort4*)(VbT + (size_t)n * 8192 + mb) = w;
        } else {
            unsigned short* dst = (mat == 0) ? Qb : Kb;
            #pragma unroll
            for (int reg = 0; reg < 4; reg++)
                dst[(size_t)(mb + reg) * 128 + n] = f2bf(acc[t][reg]);
        }
    }
    if (mat == 2) {
        #pragma unroll
        for (int i = 0; i < 8; i++) {
            int idx = tid + i * 512;
            int rr = idx >> 6, c = idx & 63;
            VbT[(size_t)(128 + rr) * 8192 + m0 + c] =
                (rr == 0) ? (unsigned short)0x3F80 : (unsigned short)0;
        }
    }
}

// ---------------------------------------------------------------------------
// Kernel 2: row norms of Q, global max row-norm^2 of K.
// ---------------------------------------------------------------------------
__global__ __launch_bounds__(128) void norms_kernel(
    const unsigned short* __restrict__ Qb, const unsigned short* __restrict__ Kb,
    float* __restrict__ qn2, unsigned* __restrict__ knmax) {
    const int r = blockIdx.x, j = threadIdx.x;
    float q = bf2f(Qb[(size_t)r * 128 + j]);
    float k = bf2f(Kb[(size_t)r * 128 + j]);
    float sq = q * q, sk = k * k;
    for (int m = 1; m < 64; m <<= 1) {
        sq += __shfl_xor(sq, m, 64);
        sk += __shfl_xor(sk, m, 64);
    }
    __shared__ float s0[2], s1[2];
    if ((j & 63) == 0) { s0[j >> 6] = sq; s1[j >> 6] = sk; }
    __syncthreads();
    if (j == 0)  qn2[r] = s0[0] + s0[1];
    if (j == 64) atomicMax(knmax, __float_as_uint(s1[0] + s1[1]));
}

// ---------------------------------------------------------------------------
// Kernel 3 v6: CVpart[sp] = C[m-range][k-range] @ V_ext^T.  M=64/block,
// ksplit 8 -> grid 1024 (4 blocks/CU).  A read fp32 directly (dist-1 reg
// prefetch, each C element read once), B via 16B DMA.  XOR-swizzled tiles.
// ---------------------------------------------------------------------------
__global__ __launch_bounds__(256, 4) void cv_kernel(
    const float* __restrict__ C, const unsigned short* __restrict__ VbT,
    float* __restrict__ CVpart) {
    __shared__ unsigned short As[64 * 64];    // 8 KB, swizzled
    __shared__ unsigned short Bs[192 * 64];   // 24 KB, swizzled
    const int tid = threadIdx.x;
    const int rg = blockIdx.x >> 3, sp = blockIdx.x & 7;
    const int m0 = rg * 64;
    const int k0 = sp * 1024;                 // 16 chunks of 64
    const int lane = tid & 63, wv = tid >> 6;
    const int mh = wv & 1, h2 = wv >> 1;
    const int ln15 = lane & 15, quad = lane >> 4;

    const int r0 = tid >> 3, gc = tid & 7;    // A slots: (r0, gc) and (r0+32, gc)
    const int gsw = gc ^ (r0 & 7);            // (r0+32)&7 == r0&7
    const float* A0 = C + (size_t)(m0 + r0) * 8192 + k0 + gc * 8;
    const float* A1 = A0 + (size_t)32 * 8192;

    float4 pa[4];
    pa[0] = *(const float4*)A0; pa[1] = *(const float4*)(A0 + 4);
    pa[2] = *(const float4*)A1; pa[3] = *(const float4*)(A1 + 4);

    f32x4 acc[2][5];
    #pragma unroll
    for (int mt = 0; mt < 2; mt++)
        #pragma unroll
        for (int t = 0; t < 5; t++) acc[mt][t] = f32x4{0.f, 0.f, 0.f, 0.f};

    const int ra0 = mh * 32 + ln15;
    const int ra1 = mh * 32 + 16 + ln15;

    for (int c = 0; c < 16; c++) {
        const int kb = c * 64;
        __syncthreads();   // previous chunk's LDS reads done
        *(bf16x8*)&As[r0 * 64 + gsw * 8]        = pack8(pa[0], pa[1]);
        *(bf16x8*)&As[(r0 + 32) * 64 + gsw * 8] = pack8(pa[2], pa[3]);
        // B DMA: 192 rows x 8 groups = 1536 slots, 6 wave-instrs
        #pragma unroll
        for (int i = 0; i < 6; i++) {
            int s = (i * 4 + wv) * 64 + lane;
            int r = s >> 3, g = (s & 7) ^ (r & 7);
            gl_lds16(VbT + (size_t)r * 8192 + k0 + kb + g * 8,
                     &Bs[(i * 4 + wv) * 512]);
        }
        if (c + 1 < 16) {   // dist-1 prefetch of next A chunk (fp32)
            const float* p0 = A0 + (c + 1) * 64;
            const float* p1 = A1 + (c + 1) * 64;
            pa[0] = *(const float4*)p0; pa[1] = *(const float4*)(p0 + 4);
            pa[2] = *(const float4*)p1; pa[3] = *(const float4*)(p1 + 4);
        }
        __syncthreads();   // DMA drained + A writes visible
        #pragma unroll
        for (int k2 = 0; k2 < 2; k2++) {
            const int lg = k2 * 4 + quad;
            bf16x8 a0 = *(const bf16x8*)&As[ra0 * 64 + ((lg ^ (ra0 & 7)) * 8)];
            bf16x8 a1 = *(const bf16x8*)&As[ra1 * 64 + ((lg ^ (ra1 & 7)) * 8)];
            #pragma unroll
            for (int t = 0; t < 5; t++) {
                int n = h2 * 80 + t * 16 + ln15;
                bf16x8 bf = *(const bf16x8*)&Bs[n * 64 + ((lg ^ (n & 7)) * 8)];
                acc[0][t] = __builtin_amdgcn_mfma_f32_16x16x32_bf16(a0, bf, acc[0][t], 0, 0, 0);
                acc[1][t] = __builtin_amdgcn_mfma_f32_16x16x32_bf16(a1, bf, acc[1][t], 0, 0, 0);
            }
        }
    }
    float* dst = CVpart + (size_t)sp * 160 * 8192;
    #pragma unroll
    for (int mt = 0; mt < 2; mt++)
        #pragma unroll
        for (int t = 0; t < 5; t++) {
            int n = h2 * 80 + t * 16 + ln15;
            int m = m0 + mh * 32 + mt * 16 + quad * 4;
            float4 w;
            w.x = acc[mt][t][0]; w.y = acc[mt][t][1];
            w.z = acc[mt][t][2]; w.w = acc[mt][t][3];
            *(float4*)(dst + (size_t)n * 8192 + m) = w;
        }
}

// ---------------------------------------------------------------------------
// Kernel 3b: CVbT bf16 = sum of 8 partials.
// ---------------------------------------------------------------------------
__global__ __launch_bounds__(256) void cvreduce_kernel(
    const float* __restrict__ CVpart, unsigned short* __restrict__ CVbT) {
    const size_t STR = (size_t)160 * 8192;
    int idx = blockIdx.x * 256 + threadIdx.x;    // 327680 float4-slots
    const float* p = CVpart + (size_t)idx * 4;
    float4 s = *(const float4*)p;
    #pragma unroll
    for (int j = 1; j < 8; j++) {
        const float4 q = *(const float4*)(p + j * STR);
        s.x += q.x; s.y += q.y; s.z += q.z; s.w += q.w;
    }
    ushort4 w;
    w.x = f2bf(s.x); w.y = f2bf(s.y); w.z = f2bf(s.z); w.w = f2bf(s.w);
    *(ushort4*)(CVbT + (size_t)idx * 4) = w;
}

// ---------------------------------------------------------------------------
// Kernel 4 v5: 256 thr, M=64, ksplit 8 -> grid 1024 (3 blocks/CU by LDS).
// Ks/Cs staged by 16B DMA into XOR-swizzled unpadded tiles; Q-frags in regs;
// partials to disjoint Opart[sp] (plain stores, no atomics).
// ---------------------------------------------------------------------------
__global__ __launch_bounds__(256, 3) void flash_kernel(
    const unsigned short* __restrict__ Qb, const unsigned short* __restrict__ Kb,
    const unsigned short* __restrict__ CVbT, const float* __restrict__ qn2,
    const unsigned* __restrict__ knmax, float* __restrict__ Opart) {
    __shared__ unsigned short Ks[64 * 128];   // 16 KB, 16-group swizzle
    __shared__ unsigned short Cs[160 * 64];   // 20 KB, 8-group swizzle
    __shared__ unsigned short Ps[64][68];     // 8.5 KB
    const int tid = threadIdx.x;
    const int rg = blockIdx.x >> 3, sp = blockIdx.x & 7;
    const int i0 = rg * 64;
    const int k0 = sp * 1024;                 // 16 chunks of 64 keys
    const int lane = tid & 63, wv = tid >> 6;
    const int ln15 = lane & 15, quad = lane >> 4;
    const int p2 = wv & 1;    // m-half: rows 32*p2..+32
    const int h2 = wv >> 1;   // QK: key-half; PV: n-half

    // Q A-fragments in registers (wave only needs its own 32 rows)
    bf16x8 qf[2][4];
    #pragma unroll
    for (int mt = 0; mt < 2; mt++)
        #pragma unroll
        for (int kk = 0; kk < 4; kk++) {
            int row = i0 + p2 * 32 + mt * 16 + ln15;
            qf[mt][kk] = *(const bf16x8*)(Qb + (size_t)row * 128 + kk * 32 + quad * 8);
        }
    const float kn2 = __uint_as_float(*knmax);
    float Msr[2][4];
    #pragma unroll
    for (int mt = 0; mt < 2; mt++)
        #pragma unroll
        for (int reg = 0; reg < 4; reg++) {
            int row = p2 * 32 + mt * 16 + quad * 4 + reg;
            Msr[mt][reg] = sqrtf(qn2[i0 + row] * kn2) * SCALE;
        }

    f32x4 acc[2][5];
    #pragma unroll
    for (int mt = 0; mt < 2; mt++)
        #pragma unroll
        for (int t = 0; t < 5; t++) acc[mt][t] = f32x4{0.f, 0.f, 0.f, 0.f};

    for (int c = 0; c < 16; c++) {
        const int kb = k0 + c * 64;
        __syncthreads();   // prev chunk's LDS reads (incl Ps) done
        // Ks DMA: 64 rows x 16 groups = 1024 slots, 4 wave-instrs
        #pragma unroll
        for (int i = 0; i < 4; i++) {
            int s = (i * 4 + wv) * 64 + lane;
            int r = s >> 4, g = (s & 15) ^ (r & 15);
            gl_lds16(Kb + (size_t)(kb + r) * 128 + g * 8, &Ks[(i * 4 + wv) * 512]);
        }
        // Cs DMA: 160 rows x 8 groups = 1280 slots, 5 wave-instrs
        #pragma unroll
        for (int i = 0; i < 5; i++) {
            int s = (i * 4 + wv) * 64 + lane;
            int r = s >> 3, g = (s & 7) ^ (r & 7);
            gl_lds16(CVbT + (size_t)r * 8192 + kb + g * 8, &Cs[(i * 4 + wv) * 512]);
        }
        __syncthreads();   // DMA drained

        // QK: rows 32*p2..+32 x keys 32*h2..+32
        f32x4 pacc[2][2];
        #pragma unroll
        for (int mt = 0; mt < 2; mt++)
            #pragma unroll
            for (int kt = 0; kt < 2; kt++) pacc[mt][kt] = f32x4{0.f, 0.f, 0.f, 0.f};
        #pragma unroll
        for (int kk = 0; kk < 4; kk++) {
            #pragma unroll
            for (int kt = 0; kt < 2; kt++) {
                int r = h2 * 32 + kt * 16 + ln15;
                int lg = kk * 4 + quad;
                bf16x8 bk = *(const bf16x8*)&Ks[r * 128 + ((lg ^ (r & 15)) * 8)];
                pacc[0][kt] = __builtin_amdgcn_mfma_f32_16x16x32_bf16(qf[0][kk], bk, pacc[0][kt], 0, 0, 0);
                pacc[1][kt] = __builtin_amdgcn_mfma_f32_16x16x32_bf16(qf[1][kk], bk, pacc[1][kt], 0, 0, 0);
            }
        }
        #pragma unroll
        for (int mt = 0; mt < 2; mt++)
            #pragma unroll
            for (int kt = 0; kt < 2; kt++)
                #pragma unroll
                for (int reg = 0; reg < 4; reg++) {
                    int row = p2 * 32 + mt * 16 + quad * 4 + reg;
                    int key = h2 * 32 + kt * 16 + ln15;
                    float p = __expf(pacc[mt][kt][reg] * SCALE - Msr[mt][reg]);
                    Ps[row][key] = f2bf(p);
                }
        __syncthreads();   // Ps visible

        // PV: rows 32*p2..+32 x n = 80*h2..+80
        #pragma unroll
        for (int ks = 0; ks < 2; ks++) {
            bf16x4 lo0 = *(const bf16x4*)&Ps[p2 * 32 + ln15][ks * 32 + quad * 8];
            bf16x4 hi0 = *(const bf16x4*)&Ps[p2 * 32 + ln15][ks * 32 + quad * 8 + 4];
            bf16x4 lo1 = *(const bf16x4*)&Ps[p2 * 32 + 16 + ln15][ks * 32 + quad * 8];
            bf16x4 hi1 = *(const bf16x4*)&Ps[p2 * 32 + 16 + ln15][ks * 32 + quad * 8 + 4];
            bf16x8 ap0, ap1;
            #pragma unroll
            for (int j = 0; j < 4; j++) {
                ap0[j] = lo0[j]; ap0[j + 4] = hi0[j];
                ap1[j] = lo1[j]; ap1[j + 4] = hi1[j];
            }
            #pragma unroll
            for (int t = 0; t < 5; t++) {
                int n = h2 * 80 + t * 16 + ln15;
                int lg = ks * 4 + quad;
                bf16x8 bc = *(const bf16x8*)&Cs[n * 64 + ((lg ^ (n & 7)) * 8)];
                acc[0][t] = __builtin_amdgcn_mfma_f32_16x16x32_bf16(ap0, bc, acc[0][t], 0, 0, 0);
                acc[1][t] = __builtin_amdgcn_mfma_f32_16x16x32_bf16(ap1, bc, acc[1][t], 0, 0, 0);
            }
        }
    }
    // epilogue: plain stores into this split's disjoint partial buffer
    float* dst = Opart + (size_t)sp * 8192 * 160;
    #pragma unroll
    for (int mt = 0; mt < 2; mt++)
        #pragma unroll
        for (int t = 0; t < 5; t++)
            #pragma unroll
            for (int reg = 0; reg < 4; reg++) {
                int row = i0 + p2 * 32 + mt * 16 + quad * 4 + reg;
                int n = h2 * 80 + t * 16 + ln15;
                dst[(size_t)row * 160 + n] = acc[mt][t][reg];
            }
}

// ---------------------------------------------------------------------------
// Kernel 5: out = elu( (sum_sp O[sp]) / (sum_sp deno[sp] + 1e-9) ).
// ---------------------------------------------------------------------------
__global__ __launch_bounds__(256) void finalize_kernel(
    const float* __restrict__ Opart, float* __restrict__ out) {
    const size_t STR = (size_t)8192 * 160;
    int idx = blockIdx.x * 256 + threadIdx.x;
    int i = idx >> 7, n = idx & 127;
    const float* p = Opart + (size_t)i * 160;
    float val = 0.f, deno = 0.f;
    #pragma unroll
    for (int sp = 0; sp < 8; sp++) {
        val  += p[sp * STR + n];
        deno += p[sp * STR + 128];
    }
    float v = val / (deno + 1e-9f);
    out[idx] = (v > 0.f) ? v : expm1f(v);
}

// ---------------------------------------------------------------------------
extern "C" void kernel_launch(void* const* d_in, const int* in_sizes, int n_in,
                              void* d_out, int out_size, void* d_ws, size_t ws_size,
                              hipStream_t stream) {
    const float* feat = (const float*)d_in[0];
    // d_in[1] = bg (unused scalar)
    const float* C    = (const float*)d_in[2];
    const float* Wq   = (const float*)d_in[3];
    const float* Wk   = (const float*)d_in[4];
    const float* Wv   = (const float*)d_in[5];
    float* out = (float*)d_out;

    char* ws = (char*)d_ws;
    unsigned short* Qb    = (unsigned short*)(ws + 0);          // 2 MB
    unsigned short* Kb    = (unsigned short*)(ws + 2097152);    // 2 MB
    unsigned short* VbT   = (unsigned short*)(ws + 4194304);    // 192x8192x2 = 3 MB
    float*          CVpart= (float*)(ws + 7340032);             // 8x160x8192x4 = 40 MB
    unsigned short* CVbT  = (unsigned short*)(ws + 49283072);   // 160x8192x2 = 2.5 MB
    float*          Opart = (float*)(ws + 51904512);            // 8x8192x160x4 = 40 MB
    float*          qn2   = (float*)(ws + 93847552);            // 32 KB
    unsigned*       knmax = (unsigned*)(ws + 93880320);         // 4 B  (~90 MB total)

    hipMemsetAsync(knmax, 0, 4, stream);
    qkv_mfma<<<dim3(128, 3), 512, 0, stream>>>(feat, Wq, Wk, Wv, Qb, Kb, VbT);
    norms_kernel<<<8192, 128, 0, stream>>>(Qb, Kb, qn2, knmax);
    cv_kernel<<<1024, 256, 0, stream>>>(C, VbT, CVpart);
    cvreduce_kernel<<<1280, 256, 0, stream>>>(CVpart, CVbT);
    flash_kernel<<<1024, 256, 0, stream>>>(Qb, Kb, CVbT, qn2, knmax, Opart);
    finalize_kernel<<<4096, 256, 0, stream>>>(Opart, out);
}